// Round 4
// baseline (1020.280 us; speedup 1.0000x reference)
//
#include <hip/hip_runtime.h>
#include <hip/hip_bf16.h>

// ---------------- problem constants ----------------
#define N_NODES   100000
#define IN_DIM    256
#define OUT_DIM   256
#define N_REL     8
#define E_PER_REL 160000
#define N_EDGES   (N_REL * E_PER_REL)      // 1,280,000
#define N_COLS    ((N_REL + 1) * OUT_DIM)  // 2304 logical: rel blocks 0..7, self block 8
#define LN_EPS    1e-5f

// column phasing: 4 phases x 64 columns; H chunk holds 9 rel-blocks x 64 cols
#define CPH 64
#define N_PHASE 4
#define HC  (9 * CPH)   // 576 cols per H row

// CSR bucket pipeline
#define NB   256                 // buckets
#define NPB  391                 // nodes per bucket (256*391 = 100096 >= 100000)
#define ECHUNK 4096              // edges per WG in count/scatter passes
#define NWGE ((N_EDGES + ECHUNK - 1) / ECHUNK)   // 313

typedef unsigned short ushort_t;
typedef unsigned int   uint_t;

typedef __attribute__((ext_vector_type(8))) __bf16    bf16x8;
typedef __attribute__((ext_vector_type(4))) float     f32x4;

__device__ __forceinline__ ushort_t f2bf(float f) {
    uint_t x = __float_as_uint(f);
    x += 0x7FFFu + ((x >> 16) & 1u);   // round-to-nearest-even
    return (ushort_t)(x >> 16);
}
__device__ __forceinline__ float bf_lo(uint_t u) { return __uint_as_float(u << 16); }
__device__ __forceinline__ float bf_hi(uint_t u) { return __uint_as_float(u & 0xFFFF0000u); }

// async global->LDS 16B copy: HW writes to wave-uniform LDS base + lane*16,
// which matches our linear-in-g LDS layout (per-lane dest == base + lane*16).
// Global source address is per-lane (carries the XOR pre-swizzle).
__device__ __forceinline__ void gload16(const void* g, void* l) {
    __builtin_amdgcn_global_load_lds(
        (const __attribute__((address_space(1))) void*)g,
        (__attribute__((address_space(3))) void*)l, 16, 0, 0);
}

// ---------------- x fp32 -> bf16 (once) ----------------
__global__ void conv_x_kernel(const float* __restrict__ x, ushort_t* __restrict__ xb) {
    int i = blockIdx.x * 256 + threadIdx.x;         // one per 8 elements
    if (i >= N_NODES * IN_DIM / 8) return;
    const float4* p = (const float4*)x + (size_t)i * 2;
    float4 f0 = p[0], f1 = p[1];
    __hip_bfloat162 h0 = __float22bfloat162_rn(make_float2(f0.x, f0.y));
    __hip_bfloat162 h1 = __float22bfloat162_rn(make_float2(f0.z, f0.w));
    __hip_bfloat162 h2 = __float22bfloat162_rn(make_float2(f1.x, f1.y));
    __hip_bfloat162 h3 = __float22bfloat162_rn(make_float2(f1.z, f1.w));
    uint4 pv;
    __builtin_memcpy(&pv.x, &h0, 4);
    __builtin_memcpy(&pv.y, &h1, 4);
    __builtin_memcpy(&pv.z, &h2, 4);
    __builtin_memcpy(&pv.w, &h3, 4);
    *(uint4*)(xb + (size_t)i * 8) = pv;
}

// ---------------- prep: BT[n][k], n = r*256+c (r<8 rel, r==8 self) ----------------
__global__ void prep_w_kernel(const float* __restrict__ Wself, const float* __restrict__ rel,
                              ushort_t* __restrict__ BT) {
    int i = blockIdx.x * 256 + threadIdx.x;   // 0 .. 2304*256-1
    if (i >= N_COLS * IN_DIM) return;
    int n = i >> 8, k = i & 255;
    int r = n >> 8, c = n & 255;
    float v = (r < N_REL) ? rel[(((r << 8) + k) << 8) + c] : Wself[(k << 8) + c];
    BT[i] = f2bf(v);
}

// ---------------- CSR build: bucketed multi-split ----------------
__global__ __launch_bounds__(256) void count_buckets(const int* __restrict__ dst,
                                                     int* __restrict__ g_bcount) {
    __shared__ int cnt[NB];
    int tid = threadIdx.x;
    cnt[tid] = 0;
    __syncthreads();
    #pragma unroll
    for (int it = 0; it < 4; ++it) {
        int e = blockIdx.x * ECHUNK + it * 1024 + tid * 4;
        if (e < N_EDGES) {
            int4 d = *(const int4*)(dst + e);
            atomicAdd(&cnt[(uint_t)d.x / NPB], 1);
            atomicAdd(&cnt[(uint_t)d.y / NPB], 1);
            atomicAdd(&cnt[(uint_t)d.z / NPB], 1);
            atomicAdd(&cnt[(uint_t)d.w / NPB], 1);
        }
    }
    __syncthreads();
    if (cnt[tid]) atomicAdd(&g_bcount[tid], cnt[tid]);
}

__global__ __launch_bounds__(256) void scan_buckets(const int* __restrict__ g_bcount,
                                                    int* __restrict__ g_bbase,
                                                    int* __restrict__ g_bcursor) {
    __shared__ int wsum[4];
    int tid = threadIdx.x, lane = tid & 63, w = tid >> 6;
    int val = g_bcount[tid];
    int x = val;
    #pragma unroll
    for (int d = 1; d < 64; d <<= 1) {
        int y = __shfl_up(x, d, 64);
        if (lane >= d) x += y;
    }
    if (lane == 63) wsum[w] = x;
    __syncthreads();
    if (tid == 0) {
        int a = 0;
        #pragma unroll
        for (int k = 0; k < 4; ++k) { int t = wsum[k]; wsum[k] = a; a += t; }
    }
    __syncthreads();
    int excl = wsum[w] + x - val;
    g_bbase[tid] = excl;
    g_bcursor[tid] = excl;
    if (tid == 255) g_bbase[256] = excl + val;
}

__global__ __launch_bounds__(256) void scatter_buckets(const int* __restrict__ src,
                                                       const int* __restrict__ dst,
                                                       int* __restrict__ g_bcursor,
                                                       uint2* __restrict__ tmp) {
    __shared__ int cnt[NB];
    __shared__ int basec[NB];
    int tid = threadIdx.x;
    cnt[tid] = 0;
    __syncthreads();
    #pragma unroll
    for (int it = 0; it < 4; ++it) {
        int e = blockIdx.x * ECHUNK + it * 1024 + tid * 4;
        if (e < N_EDGES) {
            int4 d = *(const int4*)(dst + e);
            atomicAdd(&cnt[(uint_t)d.x / NPB], 1);
            atomicAdd(&cnt[(uint_t)d.y / NPB], 1);
            atomicAdd(&cnt[(uint_t)d.z / NPB], 1);
            atomicAdd(&cnt[(uint_t)d.w / NPB], 1);
        }
    }
    __syncthreads();
    basec[tid] = cnt[tid] ? atomicAdd(&g_bcursor[tid], cnt[tid]) : 0;
    __syncthreads();
    cnt[tid] = 0;
    __syncthreads();
    #pragma unroll
    for (int it = 0; it < 4; ++it) {
        int e = blockIdx.x * ECHUNK + it * 1024 + tid * 4;
        if (e < N_EDGES) {
            int4 d = *(const int4*)(dst + e);
            int4 s = *(const int4*)(src + e);
            uint_t relb = ((uint_t)e / E_PER_REL) << 20;   // e%4==0, E_PER_REL%4==0 -> uniform
            uint_t b0 = (uint_t)d.x / NPB, b1 = (uint_t)d.y / NPB;
            uint_t b2 = (uint_t)d.z / NPB, b3 = (uint_t)d.w / NPB;
            int p0 = basec[b0] + atomicAdd(&cnt[b0], 1);
            tmp[p0] = make_uint2((uint_t)d.x, (uint_t)s.x | relb);
            int p1 = basec[b1] + atomicAdd(&cnt[b1], 1);
            tmp[p1] = make_uint2((uint_t)d.y, (uint_t)s.y | relb);
            int p2 = basec[b2] + atomicAdd(&cnt[b2], 1);
            tmp[p2] = make_uint2((uint_t)d.z, (uint_t)s.z | relb);
            int p3 = basec[b3] + atomicAdd(&cnt[b3], 1);
            tmp[p3] = make_uint2((uint_t)d.w, (uint_t)s.w | relb);
        }
    }
}

__global__ __launch_bounds__(256) void build_csr(const uint2* __restrict__ tmp,
                                                 const int* __restrict__ g_bbase,
                                                 int* __restrict__ offs,
                                                 uint_t* __restrict__ edges) {
    __shared__ int cnt[NPB];
    __shared__ int sc[512];
    int b = blockIdx.x, tid = threadIdx.x;
    int node0 = b * NPB;
    int nn = min(NPB, N_NODES - node0);
    int r0 = g_bbase[b], r1 = g_bbase[b + 1];

    for (int i = tid; i < NPB; i += 256) cnt[i] = 0;
    __syncthreads();
    for (int i = r0 + tid; i < r1; i += 256) {
        uint2 rec = tmp[i];
        atomicAdd(&cnt[rec.x - node0], 1);
    }
    __syncthreads();
    sc[tid]       = (tid < NPB) ? cnt[tid] : 0;
    sc[tid + 256] = (tid + 256 < NPB) ? cnt[tid + 256] : 0;
    __syncthreads();
    for (int d = 1; d < 512; d <<= 1) {
        int a  = (tid >= d) ? sc[tid - d] : 0;
        int a2 = (tid + 256 >= d) ? sc[tid + 256 - d] : 0;
        __syncthreads();
        sc[tid] += a; sc[tid + 256] += a2;
        __syncthreads();
    }
    for (int i = tid; i < NPB; i += 256) {
        int ex = r0 + sc[i] - cnt[i];
        if (i < nn) offs[node0 + i] = ex;
        cnt[i] = ex;
    }
    if (b == NB - 1 && tid == 0) offs[N_NODES] = r1;
    __syncthreads();
    for (int i = r0 + tid; i < r1; i += 256) {
        uint2 rec = tmp[i];
        int pos = atomicAdd(&cnt[rec.x - node0], 1);
        edges[pos] = rec.y;
    }
}

// ---------------- phase GEMM tile body (bf16 path) ----------------
#define BM 128
#define BN 64
#define BK 64
#define KT 256
#define RB 3
#define EPAD 72   // epilogue LDS row stride (shorts): 64 + 8 pad

#define NGEMM 2346                 // 3 rel-triples x 782 row-tiles
#define NGATH ((N_NODES + 3) / 4)  // 25000
#define NTOT  (NGEMM + NGATH)      // 27346

__device__ __forceinline__ void gemm_tile(int tile, const ushort_t* __restrict__ X,
                                          const ushort_t* __restrict__ B,
                                          ushort_t* __restrict__ H, int M, int c0,
                                          ushort_t* smem) {
    ushort_t* As = smem;
    const int rb0 = (tile % 3) * RB;        // rel blocks rb0..rb0+2 (0,3,6)
    const int m0  = (tile / 3) * BM;
    const int tid  = threadIdx.x;
    const int lane = tid & 63;
    const int w = tid >> 6;
    const int quad = lane >> 4, m16 = lane & 15;
    const int wm = (w & 1) * 64, wn = (w >> 1) * 32;

    f32x4 acc[RB][4][2];
    #pragma unroll
    for (int t = 0; t < RB; ++t)
        #pragma unroll
        for (int mi = 0; mi < 4; ++mi)
            #pragma unroll
            for (int ni = 0; ni < 2; ++ni)
                #pragma unroll
                for (int e = 0; e < 4; ++e) acc[t][mi][ni][e] = 0.f;

    for (int kk = 0; kk < KT; kk += BK) {
        // async direct-to-LDS staging: linear LDS dest, XOR pre-swizzle on global src
        #pragma unroll
        for (int i = 0; i < 4; ++i) {
            int g = i * 256 + tid;
            int r = g >> 3, sc2 = g & 7, c = sc2 ^ (r & 7);
            int gr = m0 + r; if (gr >= M) gr = M - 1;
            gload16(X + (size_t)gr * KT + kk + c * 8, &As[g * 8]);
        }
        #pragma unroll
        for (int t = 0; t < RB; ++t) {
            ushort_t* Bs = smem + BM * BK + t * BN * BK;
            #pragma unroll
            for (int i = 0; i < 2; ++i) {
                int g = i * 256 + tid;
                int r = g >> 3, sc2 = g & 7, c = sc2 ^ (r & 7);
                int nrow = (rb0 + t) * 256 + c0 + r;
                gload16(B + (size_t)nrow * KT + kk + c * 8, &Bs[g * 8]);
            }
        }
        __syncthreads();

        #pragma unroll
        for (int ks = 0; ks < BK; ks += 32) {
            int chunk = (ks >> 3) + quad;   // 0..7
            bf16x8 af[4];
            #pragma unroll
            for (int mi = 0; mi < 4; ++mi) {
                int row = wm + mi * 16 + m16;
                af[mi] = *(const bf16x8*)(&As[(row * 8 + (chunk ^ (row & 7))) * 8]);
            }
            #pragma unroll
            for (int t = 0; t < RB; ++t) {
                const ushort_t* Bs = smem + BM * BK + t * BN * BK;
                bf16x8 bfr[2];
                #pragma unroll
                for (int ni = 0; ni < 2; ++ni) {
                    int row = wn + ni * 16 + m16;
                    bfr[ni] = *(const bf16x8*)(&Bs[(row * 8 + (chunk ^ (row & 7))) * 8]);
                }
                #pragma unroll
                for (int mi = 0; mi < 4; ++mi)
                    #pragma unroll
                    for (int ni = 0; ni < 2; ++ni)
                        acc[t][mi][ni] = __builtin_amdgcn_mfma_f32_16x16x32_bf16(
                            af[mi], bfr[ni], acc[t][mi][ni], 0, 0, 0);
            }
        }
        __syncthreads();
    }

    // epilogue: per rel-block, transpose C through LDS, store coalesced 16B runs
    #pragma unroll
    for (int t = 0; t < RB; ++t) {
        #pragma unroll
        for (int mi = 0; mi < 4; ++mi)
            #pragma unroll
            for (int ni = 0; ni < 2; ++ni) {
                int col = wn + ni * 16 + m16;
                int rowb = wm + mi * 16 + quad * 4;
                #pragma unroll
                for (int rg = 0; rg < 4; ++rg)
                    smem[(rowb + rg) * EPAD + col] = f2bf(acc[t][mi][ni][rg]);
            }
        __syncthreads();
        #pragma unroll
        for (int i = 0; i < 4; ++i) {
            int cch = i * 256 + tid;
            int row = cch >> 3, col8 = (cch & 7) * 8;
            int grow = m0 + row;
            if (grow < M) {
                uint4 v = *(const uint4*)(&smem[row * EPAD + col8]);
                *(uint4*)(H + (size_t)grow * HC + (rb0 + t) * CPH + col8) = v;
            }
        }
        __syncthreads();
    }
}

// ---------------- gather node body: one wave per node ----------------
__device__ __forceinline__ void gather_node(int node, const ushort_t* __restrict__ H,
                                            const int* __restrict__ offs,
                                            const uint_t* __restrict__ edges,
                                            float* __restrict__ out, int c0) {
    int lane = threadIdx.x & 63;
    int grp = lane >> 3;          // edge slot 0..7
    int cs  = (lane & 7) * 8;     // col offset 0..56

    float a0 = 0.f, a1 = 0.f, a2 = 0.f, a3 = 0.f, a4 = 0.f, a5 = 0.f, a6 = 0.f, a7 = 0.f;
    if (grp == 7) {   // self block (col base 8*CPH = 512), counted once
        uint4 v = *(const uint4*)(H + (size_t)node * HC + 512 + cs);
        a0 += bf_lo(v.x); a1 += bf_hi(v.x); a2 += bf_lo(v.y); a3 += bf_hi(v.y);
        a4 += bf_lo(v.z); a5 += bf_hi(v.z); a6 += bf_lo(v.w); a7 += bf_hi(v.w);
    }
    int e0 = offs[node], e1 = offs[node + 1];
    for (int base = e0; base < e1; base += 32) {
        #pragma unroll
        for (int j = 0; j < 4; ++j) {
            int idx = base + j * 8 + grp;
            if (idx < e1) {
                uint_t r = edges[idx];
                uint4 v = *(const uint4*)(H + (size_t)(r & 0xFFFFFu) * HC + ((r >> 20) << 6) + cs);
                a0 += bf_lo(v.x); a1 += bf_hi(v.x); a2 += bf_lo(v.y); a3 += bf_hi(v.y);
                a4 += bf_lo(v.z); a5 += bf_hi(v.z); a6 += bf_lo(v.w); a7 += bf_hi(v.w);
            }
        }
    }
    #pragma unroll
    for (int off = 8; off <= 32; off <<= 1) {
        a0 += __shfl_xor(a0, off, 64); a1 += __shfl_xor(a1, off, 64);
        a2 += __shfl_xor(a2, off, 64); a3 += __shfl_xor(a3, off, 64);
        a4 += __shfl_xor(a4, off, 64); a5 += __shfl_xor(a5, off, 64);
        a6 += __shfl_xor(a6, off, 64); a7 += __shfl_xor(a7, off, 64);
    }
    if (grp == 0) {
        float* op = out + (size_t)node * OUT_DIM + c0 + cs;
        *(float4*)op       = make_float4(a0, a1, a2, a3);
        *(float4*)(op + 4) = make_float4(a4, a5, a6, a7);
    }
}

// ---------------- standalone GEMM (p0 + fp32 fallback) ----------------
template <bool BF16X>
__global__ __launch_bounds__(256) void gemm_kernel(const void* __restrict__ Xv,
                                                   const ushort_t* __restrict__ B,
                                                   ushort_t* __restrict__ H,
                                                   int M, int c0) {
    __shared__ ushort_t smem[BM * BK + RB * BN * BK];   // 40960 B
    // XCD-bijective swizzle (m204): co-locate same-A-stripe tiles per XCD
    const int nwg  = gridDim.x * gridDim.y;
    const int orig = blockIdx.y * gridDim.x + blockIdx.x;
    const int q8 = nwg >> 3, r8 = nwg & 7;
    const int xcd = orig & 7, loc = orig >> 3;
    const int swz = (xcd < r8 ? xcd * (q8 + 1) : r8 * (q8 + 1) + (xcd - r8) * q8) + loc;

    if (BF16X) {
        gemm_tile(swz, (const ushort_t*)Xv, B, H, M, c0, smem);
        return;
    }

    // fp32 fallback: reg-staged with convert
    ushort_t* As = smem;
    const int rb0 = (swz % 3) * RB;
    const int m0  = (swz / 3) * BM;
    const int tid  = threadIdx.x;
    const int lane = tid & 63, w = tid >> 6;
    const int quad = lane >> 4, m16 = lane & 15;
    const int wm = (w & 1) * 64, wn = (w >> 1) * 32;

    f32x4 acc[RB][4][2];
    #pragma unroll
    for (int t = 0; t < RB; ++t)
        #pragma unroll
        for (int mi = 0; mi < 4; ++mi)
            #pragma unroll
            for (int ni = 0; ni < 2; ++ni)
                #pragma unroll
                for (int e = 0; e < 4; ++e) acc[t][mi][ni][e] = 0.f;

    for (int kk = 0; kk < KT; kk += BK) {
        #pragma unroll
        for (int i = 0; i < 4; ++i) {
            int g = i * 256 + tid;
            int r = g >> 3, sc2 = g & 7, c = sc2 ^ (r & 7);
            int gr = m0 + r; if (gr >= M) gr = M - 1;
            const float* X = (const float*)Xv;
            const float* sp = X + (size_t)gr * KT + kk + c * 8;
            float4 f0 = *(const float4*)sp;
            float4 f1 = *(const float4*)(sp + 4);
            __hip_bfloat162 h0 = __float22bfloat162_rn(make_float2(f0.x, f0.y));
            __hip_bfloat162 h1 = __float22bfloat162_rn(make_float2(f0.z, f0.w));
            __hip_bfloat162 h2 = __float22bfloat162_rn(make_float2(f1.x, f1.y));
            __hip_bfloat162 h3 = __float22bfloat162_rn(make_float2(f1.z, f1.w));
            uint4 pv;
            __builtin_memcpy(&pv.x, &h0, 4);
            __builtin_memcpy(&pv.y, &h1, 4);
            __builtin_memcpy(&pv.z, &h2, 4);
            __builtin_memcpy(&pv.w, &h3, 4);
            *(uint4*)(&As[g * 8]) = pv;
        }
        #pragma unroll
        for (int t = 0; t < RB; ++t) {
            ushort_t* Bs = smem + BM * BK + t * BN * BK;
            #pragma unroll
            for (int i = 0; i < 2; ++i) {
                int g = i * 256 + tid;
                int r = g >> 3, sc2 = g & 7, c = sc2 ^ (r & 7);
                int nrow = (rb0 + t) * 256 + c0 + r;
                *(uint4*)(&Bs[g * 8]) = *(const uint4*)(B + (size_t)nrow * KT + kk + c * 8);
            }
        }
        __syncthreads();

        #pragma unroll
        for (int ks = 0; ks < BK; ks += 32) {
            int chunk = (ks >> 3) + quad;
            bf16x8 af[4];
            #pragma unroll
            for (int mi = 0; mi < 4; ++mi) {
                int row = wm + mi * 16 + m16;
                af[mi] = *(const bf16x8*)(&As[(row * 8 + (chunk ^ (row & 7))) * 8]);
            }
            #pragma unroll
            for (int t = 0; t < RB; ++t) {
                const ushort_t* Bs = smem + BM * BK + t * BN * BK;
                bf16x8 bfr[2];
                #pragma unroll
                for (int ni = 0; ni < 2; ++ni) {
                    int row = wn + ni * 16 + m16;
                    bfr[ni] = *(const bf16x8*)(&Bs[(row * 8 + (chunk ^ (row & 7))) * 8]);
                }
                #pragma unroll
                for (int mi = 0; mi < 4; ++mi)
                    #pragma unroll
                    for (int ni = 0; ni < 2; ++ni)
                        acc[t][mi][ni] = __builtin_amdgcn_mfma_f32_16x16x32_bf16(
                            af[mi], bfr[ni], acc[t][mi][ni], 0, 0, 0);
            }
        }
        __syncthreads();
    }

    #pragma unroll
    for (int t = 0; t < RB; ++t) {
        #pragma unroll
        for (int mi = 0; mi < 4; ++mi)
            #pragma unroll
            for (int ni = 0; ni < 2; ++ni) {
                int col = wn + ni * 16 + m16;
                int rowb = wm + mi * 16 + quad * 4;
                #pragma unroll
                for (int rg = 0; rg < 4; ++rg)
                    smem[(rowb + rg) * EPAD + col] = f2bf(acc[t][mi][ni][rg]);
            }
        __syncthreads();
        #pragma unroll
        for (int i = 0; i < 4; ++i) {
            int cch = i * 256 + tid;
            int row = cch >> 3, col8 = (cch & 7) * 8;
            int grow = m0 + row;
            if (grow < M) {
                uint4 v = *(const uint4*)(&smem[row * EPAD + col8]);
                *(uint4*)(H + (size_t)grow * HC + (rb0 + t) * CPH + col8) = v;
            }
        }
        __syncthreads();
    }
}

// ---------------- standalone gather ----------------
__global__ __launch_bounds__(256) void gather_kernel(const ushort_t* __restrict__ H,
                                                     const int* __restrict__ offs,
                                                     const uint_t* __restrict__ edges,
                                                     float* __restrict__ out, int c0) {
    int w = threadIdx.x >> 6;
    int node = blockIdx.x * 4 + w;
    if (node >= N_NODES) return;
    gather_node(node, H, offs, edges, out, c0);
}

// ---------------- fused: GEMM phase p (writes Hc) + gather phase p-1 (reads Hp) ----
// Block roles Bresenham-interleaved so CUs host MFMA-heavy and VMEM-heavy blocks
// simultaneously (m114: separate pipes overlap fully). No intra-dispatch
// communication: gather reads Hp written by a PREVIOUS dispatch.
__global__ __launch_bounds__(256) void fused_kernel(const ushort_t* __restrict__ X,
                                                    const ushort_t* __restrict__ B,
                                                    ushort_t* __restrict__ Hc, int cg,
                                                    const ushort_t* __restrict__ Hp, int cp,
                                                    const int* __restrict__ offs,
                                                    const uint_t* __restrict__ edges,
                                                    float* __restrict__ out) {
    __shared__ ushort_t smem[BM * BK + RB * BN * BK];   // 40960 B (all blocks pay it)
    const int bid = blockIdx.x;
    const int gcnt  = (int)(((long long)bid * NGEMM) / NTOT);
    const int gcnt1 = (int)(((long long)(bid + 1) * NGEMM) / NTOT);
    if (gcnt1 > gcnt) {
        // GEMM role: tile id = gcnt (each value hit exactly once)
        gemm_tile(gcnt, X, B, Hc, N_NODES, cg, smem);
    } else {
        // gather role: gather block id = bid - (#gemm blocks before bid)
        int ga = bid - gcnt;
        int node = ga * 4 + (threadIdx.x >> 6);
        if (node < N_NODES) gather_node(node, Hp, offs, edges, out, cp);
    }
}

// ---------------- in-place LayerNorm over d_out ----------------
__global__ __launch_bounds__(256) void ln_kernel(float* __restrict__ out,
                                                 const float* __restrict__ gamma,
                                                 const float* __restrict__ beta) {
    int w = threadIdx.x >> 6, lane = threadIdx.x & 63;
    int node = blockIdx.x * 4 + w;
    if (node >= N_NODES) return;
    int c4 = lane * 4;
    float4 v = *(const float4*)(out + (size_t)node * OUT_DIM + c4);
    float s = v.x + v.y + v.z + v.w;
    float q = v.x * v.x + v.y * v.y + v.z * v.z + v.w * v.w;
    #pragma unroll
    for (int off = 32; off > 0; off >>= 1) {
        s += __shfl_xor(s, off, 64);
        q += __shfl_xor(q, off, 64);
    }
    float mean = s * (1.f / 256.f);
    float var  = q * (1.f / 256.f) - mean * mean;
    float rstd = rsqrtf(var + LN_EPS);
    float4 g = *(const float4*)(gamma + c4);
    float4 b = *(const float4*)(beta + c4);
    float4 o;
    o.x = (v.x - mean) * rstd * g.x + b.x;
    o.y = (v.y - mean) * rstd * g.y + b.y;
    o.z = (v.z - mean) * rstd * g.z + b.z;
    o.w = (v.w - mean) * rstd * g.w + b.w;
    *(float4*)(out + (size_t)node * OUT_DIM + c4) = o;
}

// ---------------- launch ----------------
extern "C" void kernel_launch(void* const* d_in, const int* in_sizes, int n_in,
                              void* d_out, int out_size, void* d_ws, size_t ws_size,
                              hipStream_t stream) {
    const float* x     = (const float*)d_in[0];
    const int*   src   = (const int*)d_in[1];
    const int*   dst   = (const int*)d_in[2];
    const float* Wself = (const float*)d_in[3];
    const float* rel   = (const float*)d_in[4];
    const float* gamma = (const float*)d_in[5];
    const float* beta  = (const float*)d_in[6];
    float* out = (float*)d_out;

    char* ws = (char*)d_ws;
    constexpr size_t BT_BYTES   = (size_t)N_COLS * IN_DIM * 2;      // 1,179,648
    constexpr size_t XB_BYTES   = (size_t)N_NODES * IN_DIM * 2;     // 51,200,000
    constexpr size_t H_BYTES    = (size_t)N_NODES * HC * 2;         // 115,200,000
    constexpr size_t OFFS_BYTES = 400128;
    constexpr size_t BKT_BYTES  = 4096;
    constexpr size_t EDGE_BYTES = (size_t)N_EDGES * 4;              // 5,120,000
    constexpr size_t NEED_A = BT_BYTES + XB_BYTES + H_BYTES + OFFS_BYTES + 3 * BKT_BYTES + EDGE_BYTES;
    constexpr size_t NEED_B = NEED_A + H_BYTES;                     // + second H for ping-pong

    const bool use_xb = (ws_size >= NEED_A);
    const bool use_db = (ws_size >= NEED_B);

    size_t off = 0;
    ushort_t* BT = (ushort_t*)(ws + off); off += BT_BYTES;
    ushort_t* xb = nullptr;
    if (use_xb) { xb = (ushort_t*)(ws + off); off += XB_BYTES; }
    ushort_t* H0 = (ushort_t*)(ws + off); off += H_BYTES;
    ushort_t* H1 = nullptr;
    if (use_db) { H1 = (ushort_t*)(ws + off); off += H_BYTES; }
    uint2*    tmp     = (uint2*)H0;                // alias (dead before first gemm)
    int*      offs    = (int*)(ws + off); off += OFFS_BYTES;
    int*      bcount  = (int*)(ws + off); off += BKT_BYTES;
    int*      bbase   = (int*)(ws + off); off += BKT_BYTES;
    int*      bcursor = (int*)(ws + off); off += BKT_BYTES;
    uint_t*   edges   = (uint_t*)(ws + off);

    prep_w_kernel<<<(N_COLS * IN_DIM + 255) / 256, 256, 0, stream>>>(Wself, rel, BT);
    hipMemsetAsync(bcount, 0, NB * 4, stream);
    if (use_xb)
        conv_x_kernel<<<(N_NODES * IN_DIM / 8 + 255) / 256, 256, 0, stream>>>(x, xb);
    count_buckets<<<NWGE, 256, 0, stream>>>(dst, bcount);
    scan_buckets<<<1, 256, 0, stream>>>(bcount, bbase, bcursor);
    scatter_buckets<<<NWGE, 256, 0, stream>>>(src, dst, bcursor, tmp);
    build_csr<<<NB, 256, 0, stream>>>(tmp, bbase, offs, edges);

    if (use_db) {
        // phase pipeline with ping-pong H: gemm(p) overlapped with gather(p-1)
        dim3 g0(3, (N_NODES + BM - 1) / BM);
        gemm_kernel<true><<<g0, 256, 0, stream>>>(xb, BT, H0, N_NODES, 0);
        fused_kernel<<<NTOT, 256, 0, stream>>>(xb, BT, H1, CPH,     H0, 0,       offs, edges, out);
        fused_kernel<<<NTOT, 256, 0, stream>>>(xb, BT, H0, 2 * CPH, H1, CPH,     offs, edges, out);
        fused_kernel<<<NTOT, 256, 0, stream>>>(xb, BT, H1, 3 * CPH, H0, 2 * CPH, offs, edges, out);
        gather_kernel<<<NGATH, 256, 0, stream>>>(H1, offs, edges, out, 3 * CPH);
    } else {
        dim3 ggrid(3, (N_NODES + BM - 1) / BM);
        for (int p = 0; p < N_PHASE; ++p) {
            int c0 = p * CPH;
            if (use_xb)
                gemm_kernel<true><<<ggrid, 256, 0, stream>>>(xb, BT, H0, N_NODES, c0);
            else
                gemm_kernel<false><<<ggrid, 256, 0, stream>>>(x, BT, H0, N_NODES, c0);
            gather_kernel<<<NGATH, 256, 0, stream>>>(H0, offs, edges, out, c0);
        }
    }
    ln_kernel<<<NGATH, 256, 0, stream>>>(out, gamma, beta);
}

// Round 6
// 609.199 us; speedup vs baseline: 1.6748x; 1.6748x over previous
//
#include <hip/hip_runtime.h>
#include <hip/hip_bf16.h>

// ---------------- problem constants ----------------
#define N_NODES   100000
#define IN_DIM    256
#define OUT_DIM   256
#define N_REL     8
#define E_PER_REL 160000
#define N_EDGES   (N_REL * E_PER_REL)      // 1,280,000
#define N_COLS    ((N_REL + 1) * OUT_DIM)  // 2304 logical: rel blocks 0..7, self block 8
#define LN_EPS    1e-5f

// column phasing: 4 phases x 64 columns; H chunk holds 9 rel-blocks x 64 cols
#define CPH 64
#define N_PHASE 4
#define HC  (9 * CPH)   // 576 cols per H row

// CSR bucket pipeline
#define NB   256
#define NPB  391
#define ECHUNK 4096
#define NWGE ((N_EDGES + ECHUNK - 1) / ECHUNK)   // 313

typedef unsigned short ushort_t;
typedef unsigned int   uint_t;

typedef __attribute__((ext_vector_type(8))) __bf16    bf16x8;
typedef __attribute__((ext_vector_type(4))) float     f32x4;

__device__ __forceinline__ ushort_t f2bf(float f) {
    uint_t x = __float_as_uint(f);
    x += 0x7FFFu + ((x >> 16) & 1u);
    return (ushort_t)(x >> 16);
}
__device__ __forceinline__ float bf_lo(uint_t u) { return __uint_as_float(u << 16); }
__device__ __forceinline__ float bf_hi(uint_t u) { return __uint_as_float(u & 0xFFFF0000u); }

__device__ __forceinline__ void gload16(const void* g, void* l) {
    __builtin_amdgcn_global_load_lds(
        (const __attribute__((address_space(1))) void*)g,
        (__attribute__((address_space(3))) void*)l, 16, 0, 0);
}

// ---------------- x fp32 -> bf16 (once) ----------------
__global__ void conv_x_kernel(const float* __restrict__ x, ushort_t* __restrict__ xb) {
    int i = blockIdx.x * 256 + threadIdx.x;
    if (i >= N_NODES * IN_DIM / 8) return;
    const float4* p = (const float4*)x + (size_t)i * 2;
    float4 f0 = p[0], f1 = p[1];
    __hip_bfloat162 h0 = __float22bfloat162_rn(make_float2(f0.x, f0.y));
    __hip_bfloat162 h1 = __float22bfloat162_rn(make_float2(f0.z, f0.w));
    __hip_bfloat162 h2 = __float22bfloat162_rn(make_float2(f1.x, f1.y));
    __hip_bfloat162 h3 = __float22bfloat162_rn(make_float2(f1.z, f1.w));
    uint4 pv;
    __builtin_memcpy(&pv.x, &h0, 4);
    __builtin_memcpy(&pv.y, &h1, 4);
    __builtin_memcpy(&pv.z, &h2, 4);
    __builtin_memcpy(&pv.w, &h3, 4);
    *(uint4*)(xb + (size_t)i * 8) = pv;
}

// ---------------- prep: BT[n][k], n = r*256+c (r<8 rel, r==8 self) ----------------
__global__ void prep_w_kernel(const float* __restrict__ Wself, const float* __restrict__ rel,
                              ushort_t* __restrict__ BT) {
    int i = blockIdx.x * 256 + threadIdx.x;
    if (i >= N_COLS * IN_DIM) return;
    int n = i >> 8, k = i & 255;
    int r = n >> 8, c = n & 255;
    float v = (r < N_REL) ? rel[(((r << 8) + k) << 8) + c] : Wself[(k << 8) + c];
    BT[i] = f2bf(v);
}

// ---------------- CSR build: bucketed multi-split ----------------
__global__ __launch_bounds__(256) void count_buckets(const int* __restrict__ dst,
                                                     int* __restrict__ g_bcount) {
    __shared__ int cnt[NB];
    int tid = threadIdx.x;
    cnt[tid] = 0;
    __syncthreads();
    #pragma unroll
    for (int it = 0; it < 4; ++it) {
        int e = blockIdx.x * ECHUNK + it * 1024 + tid * 4;
        if (e < N_EDGES) {
            int4 d = *(const int4*)(dst + e);
            atomicAdd(&cnt[(uint_t)d.x / NPB], 1);
            atomicAdd(&cnt[(uint_t)d.y / NPB], 1);
            atomicAdd(&cnt[(uint_t)d.z / NPB], 1);
            atomicAdd(&cnt[(uint_t)d.w / NPB], 1);
        }
    }
    __syncthreads();
    if (cnt[tid]) atomicAdd(&g_bcount[tid], cnt[tid]);
}

__global__ __launch_bounds__(256) void scan_buckets(const int* __restrict__ g_bcount,
                                                    int* __restrict__ g_bbase,
                                                    int* __restrict__ g_bcursor) {
    __shared__ int wsum[4];
    int tid = threadIdx.x, lane = tid & 63, w = tid >> 6;
    int val = g_bcount[tid];
    int x = val;
    #pragma unroll
    for (int d = 1; d < 64; d <<= 1) {
        int y = __shfl_up(x, d, 64);
        if (lane >= d) x += y;
    }
    if (lane == 63) wsum[w] = x;
    __syncthreads();
    if (tid == 0) {
        int a = 0;
        #pragma unroll
        for (int k = 0; k < 4; ++k) { int t = wsum[k]; wsum[k] = a; a += t; }
    }
    __syncthreads();
    int excl = wsum[w] + x - val;
    g_bbase[tid] = excl;
    g_bcursor[tid] = excl;
    if (tid == 255) g_bbase[256] = excl + val;
}

__global__ __launch_bounds__(256) void scatter_buckets(const int* __restrict__ src,
                                                       const int* __restrict__ dst,
                                                       int* __restrict__ g_bcursor,
                                                       uint2* __restrict__ tmp) {
    __shared__ int cnt[NB];
    __shared__ int basec[NB];
    int tid = threadIdx.x;
    cnt[tid] = 0;
    __syncthreads();
    #pragma unroll
    for (int it = 0; it < 4; ++it) {
        int e = blockIdx.x * ECHUNK + it * 1024 + tid * 4;
        if (e < N_EDGES) {
            int4 d = *(const int4*)(dst + e);
            atomicAdd(&cnt[(uint_t)d.x / NPB], 1);
            atomicAdd(&cnt[(uint_t)d.y / NPB], 1);
            atomicAdd(&cnt[(uint_t)d.z / NPB], 1);
            atomicAdd(&cnt[(uint_t)d.w / NPB], 1);
        }
    }
    __syncthreads();
    basec[tid] = cnt[tid] ? atomicAdd(&g_bcursor[tid], cnt[tid]) : 0;
    __syncthreads();
    cnt[tid] = 0;
    __syncthreads();
    #pragma unroll
    for (int it = 0; it < 4; ++it) {
        int e = blockIdx.x * ECHUNK + it * 1024 + tid * 4;
        if (e < N_EDGES) {
            int4 d = *(const int4*)(dst + e);
            int4 s = *(const int4*)(src + e);
            uint_t relb = ((uint_t)e / E_PER_REL) << 20;
            uint_t b0 = (uint_t)d.x / NPB, b1 = (uint_t)d.y / NPB;
            uint_t b2 = (uint_t)d.z / NPB, b3 = (uint_t)d.w / NPB;
            int p0 = basec[b0] + atomicAdd(&cnt[b0], 1);
            tmp[p0] = make_uint2((uint_t)d.x, (uint_t)s.x | relb);
            int p1 = basec[b1] + atomicAdd(&cnt[b1], 1);
            tmp[p1] = make_uint2((uint_t)d.y, (uint_t)s.y | relb);
            int p2 = basec[b2] + atomicAdd(&cnt[b2], 1);
            tmp[p2] = make_uint2((uint_t)d.z, (uint_t)s.z | relb);
            int p3 = basec[b3] + atomicAdd(&cnt[b3], 1);
            tmp[p3] = make_uint2((uint_t)d.w, (uint_t)s.w | relb);
        }
    }
}

__global__ __launch_bounds__(256) void build_csr(const uint2* __restrict__ tmp,
                                                 const int* __restrict__ g_bbase,
                                                 int* __restrict__ offs,
                                                 uint_t* __restrict__ edges) {
    __shared__ int cnt[NPB];
    __shared__ int sc[512];
    int b = blockIdx.x, tid = threadIdx.x;
    int node0 = b * NPB;
    int nn = min(NPB, N_NODES - node0);
    int r0 = g_bbase[b], r1 = g_bbase[b + 1];

    for (int i = tid; i < NPB; i += 256) cnt[i] = 0;
    __syncthreads();
    for (int i = r0 + tid; i < r1; i += 256) {
        uint2 rec = tmp[i];
        atomicAdd(&cnt[rec.x - node0], 1);
    }
    __syncthreads();
    sc[tid]       = (tid < NPB) ? cnt[tid] : 0;
    sc[tid + 256] = (tid + 256 < NPB) ? cnt[tid + 256] : 0;
    __syncthreads();
    for (int d = 1; d < 512; d <<= 1) {
        int a  = (tid >= d) ? sc[tid - d] : 0;
        int a2 = (tid + 256 >= d) ? sc[tid + 256 - d] : 0;
        __syncthreads();
        sc[tid] += a; sc[tid + 256] += a2;
        __syncthreads();
    }
    for (int i = tid; i < NPB; i += 256) {
        int ex = r0 + sc[i] - cnt[i];
        if (i < nn) offs[node0 + i] = ex;
        cnt[i] = ex;
    }
    if (b == NB - 1 && tid == 0) offs[N_NODES] = r1;
    __syncthreads();
    for (int i = r0 + tid; i < r1; i += 256) {
        uint2 rec = tmp[i];
        int pos = atomicAdd(&cnt[rec.x - node0], 1);
        edges[pos] = rec.y;
    }
}

// ---------------- phase GEMM: H[M][576] = X[M][256] @ BT[sel rows][256]^T ----------
// 128 rows x 3 rel-blocks x 64 cols per block; counted-vmcnt 2-phase pipeline:
// stage tile kk+1 into the spare LDS buffer while MFMA consumes tile kk.
#define BM 128
#define BN 64
#define BK 64
#define KT 256
#define RB 3
#define EPAD 72
#define BUFSH (BM * BK + RB * BN * BK)   // 20480 shorts = 40960 B per buffer

// stage one K-tile (A 16KB + 3x B 8KB) via global_load_lds; 10 loads/thread
__device__ __forceinline__ void stage_tile(ushort_t* smem, int bufofs, int kk,
                                           int m0, int rb0, int c0, int M,
                                           const ushort_t* __restrict__ X,
                                           const ushort_t* __restrict__ B, int tid) {
    #pragma unroll
    for (int i = 0; i < 4; ++i) {
        int g = i * 256 + tid;
        int r = g >> 3, sc2 = g & 7, c = sc2 ^ (r & 7);
        int gr = m0 + r; if (gr >= M) gr = M - 1;
        gload16(X + (size_t)gr * KT + kk + c * 8, &smem[bufofs + g * 8]);
    }
    #pragma unroll
    for (int t = 0; t < RB; ++t) {
        int bofs = bufofs + BM * BK + t * BN * BK;
        #pragma unroll
        for (int i = 0; i < 2; ++i) {
            int g = i * 256 + tid;
            int r = g >> 3, sc2 = g & 7, c = sc2 ^ (r & 7);
            int nrow = (rb0 + t) * 256 + c0 + r;
            gload16(B + (size_t)nrow * KT + kk + c * 8, &smem[bofs + g * 8]);
        }
    }
}

__device__ __forceinline__ void gemm_tile(int tile, const ushort_t* __restrict__ X,
                                          const ushort_t* __restrict__ B,
                                          ushort_t* __restrict__ H, int M, int c0,
                                          ushort_t* smem) {
    const int rb0 = (tile % 3) * RB;
    const int m0  = (tile / 3) * BM;
    const int tid  = threadIdx.x;
    const int lane = tid & 63;
    const int w = tid >> 6;
    const int quad = lane >> 4, m16 = lane & 15;
    const int wm = (w & 1) * 64, wn = (w >> 1) * 32;

    f32x4 acc[RB][4][2];
    #pragma unroll
    for (int t = 0; t < RB; ++t)
        #pragma unroll
        for (int mi = 0; mi < 4; ++mi)
            #pragma unroll
            for (int ni = 0; ni < 2; ++ni)
                #pragma unroll
                for (int e = 0; e < 4; ++e) acc[t][mi][ni][e] = 0.f;

    // prologue: stage K-tile 0 into buffer 0 (10 gloads in flight)
    stage_tile(smem, 0, 0, m0, rb0, c0, M, X, B, tid);

    #pragma unroll
    for (int it = 0; it < 4; ++it) {
        const int cbuf = (it & 1) * BUFSH;
        // issue next tile's stage into the spare buffer (safe: last read of that
        // buffer was compute(it-1), sealed by it-1's trailing s_barrier)
        if (it < 3)
            stage_tile(smem, ((it + 1) & 1) * BUFSH, (it + 1) * BK, m0, rb0, c0, M, X, B, tid);
        // wait for CURRENT buffer's 10 loads (oldest); keep next's 10 in flight
        if (it < 3) asm volatile("s_waitcnt vmcnt(10)" ::: "memory");
        else        asm volatile("s_waitcnt vmcnt(0)" ::: "memory");
        __builtin_amdgcn_s_barrier();
        __builtin_amdgcn_sched_barrier(0);   // rule #18: no hoisting above the wait

        #pragma unroll
        for (int ks = 0; ks < BK; ks += 32) {
            int chunk = (ks >> 3) + quad;
            bf16x8 af[4];
            #pragma unroll
            for (int mi = 0; mi < 4; ++mi) {
                int row = wm + mi * 16 + m16;
                af[mi] = *(const bf16x8*)(&smem[cbuf + (row * 8 + (chunk ^ (row & 7))) * 8]);
            }
            #pragma unroll
            for (int t = 0; t < RB; ++t) {
                const ushort_t* Bs = smem + cbuf + BM * BK + t * BN * BK;
                bf16x8 bfr[2];
                #pragma unroll
                for (int ni = 0; ni < 2; ++ni) {
                    int row = wn + ni * 16 + m16;
                    bfr[ni] = *(const bf16x8*)(&Bs[(row * 8 + (chunk ^ (row & 7))) * 8]);
                }
                #pragma unroll
                for (int mi = 0; mi < 4; ++mi)
                    #pragma unroll
                    for (int ni = 0; ni < 2; ++ni)
                        acc[t][mi][ni] = __builtin_amdgcn_mfma_f32_16x16x32_bf16(
                            af[mi], bfr[ni], acc[t][mi][ni], 0, 0, 0);
            }
        }
        // all waves' ds_reads of cbuf retired before anyone stages over it next iter
        __builtin_amdgcn_s_barrier();
    }

    // epilogue: per rel-block, transpose C through LDS, store coalesced 16B runs
    #pragma unroll
    for (int t = 0; t < RB; ++t) {
        #pragma unroll
        for (int mi = 0; mi < 4; ++mi)
            #pragma unroll
            for (int ni = 0; ni < 2; ++ni) {
                int col = wn + ni * 16 + m16;
                int rowb = wm + mi * 16 + quad * 4;
                #pragma unroll
                for (int rg = 0; rg < 4; ++rg)
                    smem[(rowb + rg) * EPAD + col] = f2bf(acc[t][mi][ni][rg]);
            }
        __syncthreads();
        #pragma unroll
        for (int i = 0; i < 4; ++i) {
            int cch = i * 256 + tid;
            int row = cch >> 3, col8 = (cch & 7) * 8;
            int grow = m0 + row;
            if (grow < M) {
                uint4 v = *(const uint4*)(&smem[row * EPAD + col8]);
                *(uint4*)(H + (size_t)grow * HC + (rb0 + t) * CPH + col8) = v;
            }
        }
        __syncthreads();
    }
}

// ---------------- gather node body: one wave per node ----------------
__device__ __forceinline__ void gather_node(int node, const ushort_t* __restrict__ H,
                                            const int* __restrict__ offs,
                                            const uint_t* __restrict__ edges,
                                            float* __restrict__ out, int c0) {
    int lane = threadIdx.x & 63;
    int grp = lane >> 3;
    int cs  = (lane & 7) * 8;

    float a0 = 0.f, a1 = 0.f, a2 = 0.f, a3 = 0.f, a4 = 0.f, a5 = 0.f, a6 = 0.f, a7 = 0.f;
    if (grp == 7) {
        uint4 v = *(const uint4*)(H + (size_t)node * HC + 512 + cs);
        a0 += bf_lo(v.x); a1 += bf_hi(v.x); a2 += bf_lo(v.y); a3 += bf_hi(v.y);
        a4 += bf_lo(v.z); a5 += bf_hi(v.z); a6 += bf_lo(v.w); a7 += bf_hi(v.w);
    }
    int e0 = offs[node], e1 = offs[node + 1];
    for (int base = e0; base < e1; base += 32) {
        #pragma unroll
        for (int j = 0; j < 4; ++j) {
            int idx = base + j * 8 + grp;
            if (idx < e1) {
                uint_t r = edges[idx];
                uint4 v = *(const uint4*)(H + (size_t)(r & 0xFFFFFu) * HC + ((r >> 20) << 6) + cs);
                a0 += bf_lo(v.x); a1 += bf_hi(v.x); a2 += bf_lo(v.y); a3 += bf_hi(v.y);
                a4 += bf_lo(v.z); a5 += bf_hi(v.z); a6 += bf_lo(v.w); a7 += bf_hi(v.w);
            }
        }
    }
    #pragma unroll
    for (int off = 8; off <= 32; off <<= 1) {
        a0 += __shfl_xor(a0, off, 64); a1 += __shfl_xor(a1, off, 64);
        a2 += __shfl_xor(a2, off, 64); a3 += __shfl_xor(a3, off, 64);
        a4 += __shfl_xor(a4, off, 64); a5 += __shfl_xor(a5, off, 64);
        a6 += __shfl_xor(a6, off, 64); a7 += __shfl_xor(a7, off, 64);
    }
    if (grp == 0) {
        float* op = out + (size_t)node * OUT_DIM + c0 + cs;
        *(float4*)op       = make_float4(a0, a1, a2, a3);
        *(float4*)(op + 4) = make_float4(a4, a5, a6, a7);
    }
}

// ---------------- standalone GEMM ----------------
template <bool BF16X>
__global__ __launch_bounds__(256) void gemm_kernel(const void* __restrict__ Xv,
                                                   const ushort_t* __restrict__ B,
                                                   ushort_t* __restrict__ H,
                                                   int M, int c0) {
    __shared__ ushort_t smem[BF16X ? 2 * BUFSH : BUFSH];
    // XCD-bijective swizzle (m204)
    const int nwg  = gridDim.x * gridDim.y;
    const int orig = blockIdx.y * gridDim.x + blockIdx.x;
    const int q8 = nwg >> 3, r8 = nwg & 7;
    const int xcd = orig & 7, loc = orig >> 3;
    const int swz = (xcd < r8 ? xcd * (q8 + 1) : r8 * (q8 + 1) + (xcd - r8) * q8) + loc;

    if (BF16X) {
        gemm_tile(swz, (const ushort_t*)Xv, B, H, M, c0, smem);
        return;
    }

    // fp32 fallback: reg-staged with convert (single buffer, 2-barrier loop)
    ushort_t* As = smem;
    const int rb0 = (swz % 3) * RB;
    const int m0  = (swz / 3) * BM;
    const int tid  = threadIdx.x;
    const int lane = tid & 63, w = tid >> 6;
    const int quad = lane >> 4, m16 = lane & 15;
    const int wm = (w & 1) * 64, wn = (w >> 1) * 32;

    f32x4 acc[RB][4][2];
    #pragma unroll
    for (int t = 0; t < RB; ++t)
        #pragma unroll
        for (int mi = 0; mi < 4; ++mi)
            #pragma unroll
            for (int ni = 0; ni < 2; ++ni)
                #pragma unroll
                for (int e = 0; e < 4; ++e) acc[t][mi][ni][e] = 0.f;

    for (int kk = 0; kk < KT; kk += BK) {
        #pragma unroll
        for (int i = 0; i < 4; ++i) {
            int g = i * 256 + tid;
            int r = g >> 3, sc2 = g & 7, c = sc2 ^ (r & 7);
            int gr = m0 + r; if (gr >= M) gr = M - 1;
            const float* X = (const float*)Xv;
            const float* sp = X + (size_t)gr * KT + kk + c * 8;
            float4 f0 = *(const float4*)sp;
            float4 f1 = *(const float4*)(sp + 4);
            __hip_bfloat162 h0 = __float22bfloat162_rn(make_float2(f0.x, f0.y));
            __hip_bfloat162 h1 = __float22bfloat162_rn(make_float2(f0.z, f0.w));
            __hip_bfloat162 h2 = __float22bfloat162_rn(make_float2(f1.x, f1.y));
            __hip_bfloat162 h3 = __float22bfloat162_rn(make_float2(f1.z, f1.w));
            uint4 pv;
            __builtin_memcpy(&pv.x, &h0, 4);
            __builtin_memcpy(&pv.y, &h1, 4);
            __builtin_memcpy(&pv.z, &h2, 4);
            __builtin_memcpy(&pv.w, &h3, 4);
            *(uint4*)(&As[g * 8]) = pv;
        }
        #pragma unroll
        for (int t = 0; t < RB; ++t) {
            ushort_t* Bs = smem + BM * BK + t * BN * BK;
            #pragma unroll
            for (int i = 0; i < 2; ++i) {
                int g = i * 256 + tid;
                int r = g >> 3, sc2 = g & 7, c = sc2 ^ (r & 7);
                int nrow = (rb0 + t) * 256 + c0 + r;
                *(uint4*)(&Bs[g * 8]) = *(const uint4*)(B + (size_t)nrow * KT + kk + c * 8);
            }
        }
        __syncthreads();

        #pragma unroll
        for (int ks = 0; ks < BK; ks += 32) {
            int chunk = (ks >> 3) + quad;
            bf16x8 af[4];
            #pragma unroll
            for (int mi = 0; mi < 4; ++mi) {
                int row = wm + mi * 16 + m16;
                af[mi] = *(const bf16x8*)(&As[(row * 8 + (chunk ^ (row & 7))) * 8]);
            }
            #pragma unroll
            for (int t = 0; t < RB; ++t) {
                const ushort_t* Bs = smem + BM * BK + t * BN * BK;
                bf16x8 bfr[2];
                #pragma unroll
                for (int ni = 0; ni < 2; ++ni) {
                    int row = wn + ni * 16 + m16;
                    bfr[ni] = *(const bf16x8*)(&Bs[(row * 8 + (chunk ^ (row & 7))) * 8]);
                }
                #pragma unroll
                for (int mi = 0; mi < 4; ++mi)
                    #pragma unroll
                    for (int ni = 0; ni < 2; ++ni)
                        acc[t][mi][ni] = __builtin_amdgcn_mfma_f32_16x16x32_bf16(
                            af[mi], bfr[ni], acc[t][mi][ni], 0, 0, 0);
            }
        }
        __syncthreads();
    }

    #pragma unroll
    for (int t = 0; t < RB; ++t) {
        #pragma unroll
        for (int mi = 0; mi < 4; ++mi)
            #pragma unroll
            for (int ni = 0; ni < 2; ++ni) {
                int col = wn + ni * 16 + m16;
                int rowb = wm + mi * 16 + quad * 4;
                #pragma unroll
                for (int rg = 0; rg < 4; ++rg)
                    smem[(rowb + rg) * EPAD + col] = f2bf(acc[t][mi][ni][rg]);
            }
        __syncthreads();
        #pragma unroll
        for (int i = 0; i < 4; ++i) {
            int cch = i * 256 + tid;
            int row = cch >> 3, col8 = (cch & 7) * 8;
            int grow = m0 + row;
            if (grow < M) {
                uint4 v = *(const uint4*)(&smem[row * EPAD + col8]);
                *(uint4*)(H + (size_t)grow * HC + (rb0 + t) * CPH + col8) = v;
            }
        }
        __syncthreads();
    }
}

// ---------------- standalone gather ----------------
__global__ __launch_bounds__(256) void gather_kernel(const ushort_t* __restrict__ H,
                                                     const int* __restrict__ offs,
                                                     const uint_t* __restrict__ edges,
                                                     float* __restrict__ out, int c0) {
    int w = threadIdx.x >> 6;
    int node = blockIdx.x * 4 + w;
    if (node >= N_NODES) return;
    gather_node(node, H, offs, edges, out, c0);
}

// ---------------- in-place LayerNorm over d_out ----------------
__global__ __launch_bounds__(256) void ln_kernel(float* __restrict__ out,
                                                 const float* __restrict__ gamma,
                                                 const float* __restrict__ beta) {
    int w = threadIdx.x >> 6, lane = threadIdx.x & 63;
    int node = blockIdx.x * 4 + w;
    if (node >= N_NODES) return;
    int c4 = lane * 4;
    float4 v = *(const float4*)(out + (size_t)node * OUT_DIM + c4);
    float s = v.x + v.y + v.z + v.w;
    float q = v.x * v.x + v.y * v.y + v.z * v.z + v.w * v.w;
    #pragma unroll
    for (int off = 32; off > 0; off >>= 1) {
        s += __shfl_xor(s, off, 64);
        q += __shfl_xor(q, off, 64);
    }
    float mean = s * (1.f / 256.f);
    float var  = q * (1.f / 256.f) - mean * mean;
    float rstd = rsqrtf(var + LN_EPS);
    float4 g = *(const float4*)(gamma + c4);
    float4 b = *(const float4*)(beta + c4);
    float4 o;
    o.x = (v.x - mean) * rstd * g.x + b.x;
    o.y = (v.y - mean) * rstd * g.y + b.y;
    o.z = (v.z - mean) * rstd * g.z + b.z;
    o.w = (v.w - mean) * rstd * g.w + b.w;
    *(float4*)(out + (size_t)node * OUT_DIM + c4) = o;
}

// ---------------- launch ----------------
extern "C" void kernel_launch(void* const* d_in, const int* in_sizes, int n_in,
                              void* d_out, int out_size, void* d_ws, size_t ws_size,
                              hipStream_t stream) {
    const float* x     = (const float*)d_in[0];
    const int*   src   = (const int*)d_in[1];
    const int*   dst   = (const int*)d_in[2];
    const float* Wself = (const float*)d_in[3];
    const float* rel   = (const float*)d_in[4];
    const float* gamma = (const float*)d_in[5];
    const float* beta  = (const float*)d_in[6];
    float* out = (float*)d_out;

    char* ws = (char*)d_ws;
    constexpr size_t BT_BYTES   = (size_t)N_COLS * IN_DIM * 2;
    constexpr size_t XB_BYTES   = (size_t)N_NODES * IN_DIM * 2;
    constexpr size_t H_BYTES    = (size_t)N_NODES * HC * 2;
    constexpr size_t OFFS_BYTES = 400128;
    constexpr size_t BKT_BYTES  = 4096;
    constexpr size_t EDGE_BYTES = (size_t)N_EDGES * 4;
    constexpr size_t NEED_A = BT_BYTES + XB_BYTES + H_BYTES + OFFS_BYTES + 3 * BKT_BYTES + EDGE_BYTES;

    const bool use_xb = (ws_size >= NEED_A);

    size_t off = 0;
    ushort_t* BT = (ushort_t*)(ws + off); off += BT_BYTES;
    ushort_t* xb = nullptr;
    if (use_xb) { xb = (ushort_t*)(ws + off); off += XB_BYTES; }
    ushort_t* H       = (ushort_t*)(ws + off); off += H_BYTES;
    uint2*    tmp     = (uint2*)H;
    int*      offs    = (int*)(ws + off); off += OFFS_BYTES;
    int*      bcount  = (int*)(ws + off); off += BKT_BYTES;
    int*      bbase   = (int*)(ws + off); off += BKT_BYTES;
    int*      bcursor = (int*)(ws + off); off += BKT_BYTES;
    uint_t*   edges   = (uint_t*)(ws + off);

    prep_w_kernel<<<(N_COLS * IN_DIM + 255) / 256, 256, 0, stream>>>(Wself, rel, BT);
    hipMemsetAsync(bcount, 0, NB * 4, stream);
    if (use_xb)
        conv_x_kernel<<<(N_NODES * IN_DIM / 8 + 255) / 256, 256, 0, stream>>>(x, xb);
    count_buckets<<<NWGE, 256, 0, stream>>>(dst, bcount);
    scan_buckets<<<1, 256, 0, stream>>>(bcount, bbase, bcursor);
    scatter_buckets<<<NWGE, 256, 0, stream>>>(src, dst, bcursor, tmp);
    build_csr<<<NB, 256, 0, stream>>>(tmp, bbase, offs, edges);

    dim3 ggrid(3, (N_NODES + BM - 1) / BM);
    for (int p = 0; p < N_PHASE; ++p) {
        int c0 = p * CPH;
        if (use_xb)
            gemm_kernel<true><<<ggrid, 256, 0, stream>>>(xb, BT, H, N_NODES, c0);
        else
            gemm_kernel<false><<<ggrid, 256, 0, stream>>>(x, BT, H, N_NODES, c0);
        gather_kernel<<<(N_NODES + 3) / 4, 256, 0, stream>>>(H, offs, edges, out, c0);
    }
    ln_kernel<<<(N_NODES + 3) / 4, 256, 0, stream>>>(out, gamma, beta);
}